// Round 3
// baseline (253.934 us; speedup 1.0000x reference)
//
#include <hip/hip_runtime.h>

#define EPSF 1e-10f
#define KPN 32
#define HH 96
#define WW 96
#define NPIX (HH*WW)     // 9216
#define CH 3
#define SH 128
#define SW 128
#define NIMG 64

__device__ inline float wred_sum(float v){
  #pragma unroll
  for(int off=32; off; off>>=1) v += __shfl_xor(v, off, 64);
  return v;
}
__device__ inline float wred_max(float v){
  #pragma unroll
  for(int off=32; off; off>>=1) v = fmaxf(v, __shfl_xor(v, off, 64));
  return v;
}

// ---------------- resize: jax.image.resize bilinear, antialias=True, 128->96 ----------------
__global__ __launch_bounds__(256) void k_resize(const float* __restrict__ img, float* __restrict__ out){
  int idx = blockIdx.x*256 + threadIdx.x;
  if (idx >= NIMG*CH*NPIX) return;
  int ox = idx % WW;
  int oy = (idx / WW) % HH;
  int nc = idx / NPIX;
  float xs = (ox + 0.5f)*(4.0f/3.0f) - 0.5f;
  float ys = (oy + 0.5f)*(4.0f/3.0f) - 0.5f;
  int jx0 = (int)ceilf(xs - 4.0f/3.0f);
  int jy0 = (int)ceilf(ys - 4.0f/3.0f);
  float wx[3], wy[3]; float sx=0.f, sy=0.f;
  #pragma unroll
  for(int t=0;t<3;t++){
    int j = jx0+t;
    float w = 1.0f - 0.75f*fabsf((float)j - xs);
    w = (j>=0 && j<SW) ? fmaxf(w,0.0f) : 0.0f;
    wx[t]=w; sx+=w;
    j = jy0+t;
    w = 1.0f - 0.75f*fabsf((float)j - ys);
    w = (j>=0 && j<SH) ? fmaxf(w,0.0f) : 0.0f;
    wy[t]=w; sy+=w;
  }
  float inv = 1.0f/(sx*sy);
  const float* base = img + (size_t)nc*SH*SW;
  float acc=0.f;
  #pragma unroll
  for(int ty=0;ty<3;ty++){
    if (wy[ty]==0.f) continue;
    int jy = min(max(jy0+ty,0), SH-1);
    #pragma unroll
    for(int tx=0;tx<3;tx++){
      if (wx[tx]==0.f) continue;
      int jx = min(max(jx0+tx,0), SW-1);
      acc += wy[ty]*wx[tx]*base[jy*SW+jx];
    }
  }
  out[idx] = acc*inv;
}

// ---------------- local entropy (LDS-free, 2x2 outputs/thread, 4x4 reg halo) ----------------
__global__ __launch_bounds__(256) void k_entropy(const float* __restrict__ rimg, float* __restrict__ ent){
  int tid = threadIdx.x;
  int n = blockIdx.y;
  int idx = blockIdx.x*256 + tid;    // 0..2303
  int rg = idx / 48, cg = idx % 48;
  int r0 = rg*2, c0 = cg*2;
  float entacc[2][2] = {{0.f,0.f},{0.f,0.f}};
  for (int ch=0; ch<CH; ++ch){
    const float* src = rimg + ((size_t)(n*CH+ch))*NPIX;
    float cur[4][4], stp[4][4];
    #pragma unroll
    for (int r=0;r<4;r++){
      int gr = r0-1+r;
      bool rok = (gr>=0 && gr<HH);
      #pragma unroll
      for (int c=0;c<4;c++){
        int gc = c0-1+c;
        if (rok && gc>=0 && gc<WW){
          float v = src[gr*96+gc];
          cur[r][c] = __expf(-50.f*v*v);
          stp[r][c] = __expf(6.6666667f*v);
        } else { cur[r][c]=0.f; stp[r][c]=1.f; }
      }
    }
    float S[2][2]={{0.f,0.f},{0.f,0.f}}, T[2][2]={{0.f,0.f},{0.f,0.f}};
    float rb = __expf(-0.22222222f);
    const float r2m = rb*rb;
    #pragma unroll
    for (int b=0;b<16;b++){
      float vs[2][4];
      #pragma unroll
      for (int rr=0;rr<2;rr++)
        #pragma unroll
        for (int c=0;c<4;c++)
          vs[rr][c] = cur[rr][c]+cur[rr+1][c]+cur[rr+2][c];
      #pragma unroll
      for (int rr=0;rr<2;rr++)
        #pragma unroll
        for (int cc=0;cc<2;cc++){
          float p = (vs[rr][cc]+vs[rr][cc+1]+vs[rr][cc+2])*(1.f/9.f);
          S[rr][cc] += p;
          T[rr][cc] += p*__logf(p+EPSF);
        }
      if (b<15){
        float m = rb;
        #pragma unroll
        for (int r=0;r<4;r++)
          #pragma unroll
          for (int c=0;c<4;c++)
            cur[r][c] *= stp[r][c]*m;
        rb *= r2m;
      }
    }
    #pragma unroll
    for (int rr=0;rr<2;rr++)
      #pragma unroll
      for (int cc=0;cc<2;cc++){
        float Sp = S[rr][cc]+EPSF;
        entacc[rr][cc] += __logf(Sp) - T[rr][cc]/Sp;
      }
  }
  #pragma unroll
  for (int rr=0;rr<2;rr++)
    #pragma unroll
    for (int cc=0;cc<2;cc++)
      ent[(size_t)n*NPIX + (size_t)(r0+rr)*96 + (c0+cc)] = entacc[rr][cc]*(1.f/3.f);
}

// ---------------- main pass A: kp-chunked gaussian streaming ----------------
__global__ __launch_bounds__(256, 4) void k_mainA(const float* __restrict__ gauss,
                                                  const float* __restrict__ status,
                                                  const float* __restrict__ ent,
                                                  float* __restrict__ amB,
                                                  float* __restrict__ agB,
                                                  float* __restrict__ miS,
                                                  float* __restrict__ hsG){
  int tid = threadIdx.x;
  int lane = tid & 63;
  int tile = blockIdx.x;   // 0..17
  int b = blockIdx.y;      // 0..15
  int kpc = blockIdx.z;    // 0..3
  int p2 = tile*256 + tid; // float2 index in 4608-wide plane
  const float2* g2 = (const float2*)gauss;
  const float2* e2 = (const float2*)ent;
  float2 re[4], se[4], ce[4];
  #pragma unroll
  for (int s=0;s<4;s++) re[s] = e2[(size_t)(b*4+s)*4608 + p2];
  #pragma unroll
  for (int s=0;s<4;s++){
    se[s] = re[(s+3)&3];
    ce[s].x = fmaxf(re[s].x, se[s].x) - se[s].x;
    ce[s].y = fmaxf(re[s].y, se[s].y) - se[s].y;
  }
  float2 am[4], ag[4], mi[4];
  #pragma unroll
  for (int s=0;s<4;s++){ am[s]=make_float2(0,0); ag[s]=make_float2(0,0); mi[s]=make_float2(0,0); }
  float hsacc = 0.f;
  #pragma unroll 4
  for (int k=0;k<8;k++){
    float2 ah[4];
    #pragma unroll
    for (int s=0;s<4;s++){
      float2 g = g2[((size_t)((b*4+s)*32 + kpc*8 + k))*4608 + p2];
      float st = status[b*128 + s*32 + kpc*8 + k];
      float hx = fminf(fmaxf(g.x - 0.1f, 0.f)*3.5f, 1.f);
      float hy = fminf(fmaxf(g.y - 0.1f, 0.f)*3.5f, 1.f);
      if (b==0 && kpc==0 && k==0 && s==0) hsacc = hx + hy;
      ah[s].x = st*hx; ah[s].y = st*hy;
      am[s].x += ah[s].x; am[s].y += ah[s].y;
      ag[s].x += g.x;     ag[s].y += g.y;
    }
    #pragma unroll
    for (int s=0;s<4;s++){
      float2 sh = ah[(s+3)&3];
      float rx = se[s].x*(1.f-ah[s].x)*(1.f-sh.x) + re[s].x*ah[s].x + ce[s].x*(1.f-ah[s].x);
      float ry = se[s].y*(1.f-ah[s].y)*(1.f-sh.y) + re[s].y*ah[s].y + ce[s].y*(1.f-ah[s].y);
      mi[s].x += fminf(rx, re[s].x);
      mi[s].y += fminf(ry, re[s].y);
    }
  }
  #pragma unroll
  for (int s=0;s<4;s++){
    int base = (b*4+s)*9216 + p2*2;
    atomicAdd(&amB[base],   am[s].x);
    atomicAdd(&amB[base+1], am[s].y);
    atomicAdd(&agB[base],   ag[s].x);
    atomicAdd(&agB[base+1], ag[s].y);
    float r = wred_sum(mi[s].x + mi[s].y);
    if (lane==0) atomicAdd(&miS[b*4+s], r);
  }
  if (b==0 && kpc==0){
    float h = wred_sum(hsacc);
    if (lane==0) atomicAdd(hsG, h);
  }
}

// ---------------- main pass B: mel/mcel/gmax from aggregated am/ag ----------------
__global__ __launch_bounds__(256) void k_mainB(const float* __restrict__ amB,
                                               const float* __restrict__ agB,
                                               const float* __restrict__ ent,
                                               float* __restrict__ melN,
                                               float* __restrict__ mcelN,
                                               float* __restrict__ reS,
                                               float* __restrict__ ceS,
                                               unsigned int* __restrict__ gmax){
  int tid = threadIdx.x;
  int lane = tid & 63;
  int tile = blockIdx.x;   // 0..17
  int b = blockIdx.y;      // 0..15
  int p2 = tile*256 + tid;
  const float2* e2 = (const float2*)ent;
  const float2* am2 = (const float2*)amB;
  const float2* ag2 = (const float2*)agB;
  float2 re[4], se[4], ce[4];
  #pragma unroll
  for (int s=0;s<4;s++) re[s] = e2[(size_t)(b*4+s)*4608 + p2];
  #pragma unroll
  for (int s=0;s<4;s++){
    se[s] = re[(s+3)&3];
    ce[s].x = fmaxf(re[s].x, se[s].x) - se[s].x;
    ce[s].y = fmaxf(re[s].y, se[s].y) - se[s].y;
  }
  #pragma unroll
  for (int s=0;s<4;s++){
    float2 am = am2[(size_t)(b*4+s)*4608 + p2];
    float2 ag = ag2[(size_t)(b*4+s)*4608 + p2];
    float qx = 1.f - fminf(am.x, 1.f);
    float qy = 1.f - fminf(am.y, 1.f);
    float r1 = wred_sum(re[s].x*qx + re[s].y*qy);
    float r2 = wred_sum(ce[s].x*qx + ce[s].y*qy);
    float r3 = wred_sum(re[s].x + re[s].y);
    float r4 = wred_sum(ce[s].x + ce[s].y);
    float r5 = wred_max(fmaxf(ag.x, ag.y));
    if (lane==0){
      atomicAdd(&melN[b*4+s], r1);
      atomicAdd(&mcelN[b*4+s], r2);
      atomicAdd(&reS[b*4+s], r3);
      atomicAdd(&ceS[b*4+s], r4);
      atomicMax(&gmax[b*4+s], __float_as_uint(r5));
    }
  }
}

// ---------------- finalization ----------------
__global__ __launch_bounds__(256) void k_final(const float* __restrict__ coords,
                                               const float* __restrict__ status,
                                               const float* __restrict__ miS,
                                               const float* __restrict__ melN,
                                               const float* __restrict__ mcelN,
                                               const float* __restrict__ reS,
                                               const float* __restrict__ ceS,
                                               const unsigned int* __restrict__ gmax,
                                               const float* __restrict__ hsG,
                                               float* __restrict__ out){
  __shared__ float wsum[4];
  int tid = threadIdx.x;
  int n = tid >> 2, q = tid & 3;   // n in 0..63, q selects 8 kp
  int s = n & 3;
  int np = (s==0) ? n+3 : n-1;
  float mc = 0.f, sl = 0.f;
  #pragma unroll
  for (int j=0;j<8;j++){
    int kp = q*8 + j;
    float dx = coords[(n*KPN+kp)*2+0] - coords[(np*KPN+kp)*2+0];
    float dy = coords[(n*KPN+kp)*2+1] - coords[(np*KPN+kp)*2+1];
    float st = status[n*KPN+kp];
    mc += sqrtf(dx*dx+dy*dy) * st * status[np*KPN+kp];
    sl += st;
  }
  mc += __shfl_xor(mc,1,64); mc += __shfl_xor(mc,2,64);
  sl += __shfl_xor(sl,1,64); sl += __shfl_xor(sl,2,64);
  float mint = 0.f;
  if (q==0){
    sl *= (1.f/KPN);
    float rsum = reS[n];
    float mel = melN[n]/(rsum+EPSF);
    float mcel = (s==0) ? 0.f : mcelN[n]/(ceS[n]+EPSF);
    float rc = (rsum - miS[n]*(1.f/KPN)) / hsG[0];
    float itl = rc + 0.1f*mc;
    float ovl = fmaxf(__uint_as_float(gmax[n]) - 1.5f, 0.f)*(1.f/KPN);
    mint = 100.f*mel + 100.f*mcel + itl + 10.f*ovl + (1.f-mel)*2.5f*sl;
  }
  float r = wred_sum(mint);
  if ((tid&63)==0) wsum[tid>>6] = r;
  __syncthreads();
  if (tid==0) out[0] = (wsum[0]+wsum[1]+wsum[2]+wsum[3])*(1.f/64.f);
}

extern "C" void kernel_launch(void* const* d_in, const int* in_sizes, int n_in,
                              void* d_out, int out_size, void* d_ws, size_t ws_size,
                              hipStream_t stream){
  const float* coords = (const float*)d_in[0];
  const float* gauss  = (const float*)d_in[1];
  const float* status = (const float*)d_in[2];
  const float* images = (const float*)d_in[3];
  float* out = (float*)d_out;
  float* rimg = (float*)d_ws;                          // 1,769,472 f32
  float* ent  = rimg + (size_t)NIMG*CH*NPIX;           // 589,824 f32
  float* amB  = ent + (size_t)NIMG*NPIX;               // 589,824 f32
  float* agB  = amB + (size_t)NIMG*NPIX;               // 589,824 f32
  float* miS  = agB + (size_t)NIMG*NPIX;               // 64
  float* melN = miS + 64;
  float* mcelN = melN + 64;
  float* reS   = mcelN + 64;
  float* ceS   = reS + 64;
  unsigned int* gmax = (unsigned int*)(ceS + 64);      // 64
  float* hsG = (float*)(gmax + 64);                    // 1
  size_t zero_bytes = ((size_t)2*NIMG*NPIX + 6*64 + 1) * 4;
  hipMemsetAsync(amB, 0, zero_bytes, stream);
  k_resize<<<(NIMG*CH*NPIX + 255)/256, 256, 0, stream>>>(images, rimg);
  k_entropy<<<dim3(9,64), 256, 0, stream>>>(rimg, ent);
  k_mainA<<<dim3(18,16,4), 256, 0, stream>>>(gauss, status, ent, amB, agB, miS, hsG);
  k_mainB<<<dim3(18,16), 256, 0, stream>>>(amB, agB, ent, melN, mcelN, reS, ceS, gmax);
  k_final<<<1,256,0,stream>>>(coords, status, miS, melN, mcelN, reS, ceS, gmax, hsG, out);
}

// Round 4
// 126.344 us; speedup vs baseline: 2.0099x; 2.0099x over previous
//
#include <hip/hip_runtime.h>

#define EPSF 1e-10f
#define KPN 32
#define HH 96
#define WW 96
#define NPIX (HH*WW)     // 9216
#define CH 3
#define SH 128
#define SW 128
#define NIMG 64

__device__ inline float wred_sum(float v){
  #pragma unroll
  for(int off=32; off; off>>=1) v += __shfl_xor(v, off, 64);
  return v;
}
__device__ inline float wred_max(float v){
  #pragma unroll
  for(int off=32; off; off>>=1) v = fmaxf(v, __shfl_xor(v, off, 64));
  return v;
}

// ---------------- resize: jax.image.resize bilinear, antialias=True, 128->96 ----------------
__global__ __launch_bounds__(256) void k_resize(const float* __restrict__ img, float* __restrict__ out){
  int idx = blockIdx.x*256 + threadIdx.x;
  if (idx >= NIMG*CH*NPIX) return;
  int ox = idx % WW;
  int oy = (idx / WW) % HH;
  int nc = idx / NPIX;
  float xs = (ox + 0.5f)*(4.0f/3.0f) - 0.5f;
  float ys = (oy + 0.5f)*(4.0f/3.0f) - 0.5f;
  int jx0 = (int)ceilf(xs - 4.0f/3.0f);
  int jy0 = (int)ceilf(ys - 4.0f/3.0f);
  float wx[3], wy[3]; float sx=0.f, sy=0.f;
  #pragma unroll
  for(int t=0;t<3;t++){
    int j = jx0+t;
    float w = 1.0f - 0.75f*fabsf((float)j - xs);
    w = (j>=0 && j<SW) ? fmaxf(w,0.0f) : 0.0f;
    wx[t]=w; sx+=w;
    j = jy0+t;
    w = 1.0f - 0.75f*fabsf((float)j - ys);
    w = (j>=0 && j<SH) ? fmaxf(w,0.0f) : 0.0f;
    wy[t]=w; sy+=w;
  }
  float inv = 1.0f/(sx*sy);
  const float* base = img + (size_t)nc*SH*SW;
  float acc=0.f;
  #pragma unroll
  for(int ty=0;ty<3;ty++){
    if (wy[ty]==0.f) continue;
    int jy = min(max(jy0+ty,0), SH-1);
    #pragma unroll
    for(int tx=0;tx<3;tx++){
      if (wx[tx]==0.f) continue;
      int jx = min(max(jx0+tx,0), SW-1);
      acc += wy[ty]*wx[tx]*base[jy*SW+jx];
    }
  }
  out[idx] = acc*inv;
}

// ---------------- local entropy (LDS-free, 2x2 outputs/thread, 4x4 reg halo) ----------------
__global__ __launch_bounds__(256) void k_entropy(const float* __restrict__ rimg, float* __restrict__ ent){
  int tid = threadIdx.x;
  int n = blockIdx.y;
  int idx = blockIdx.x*256 + tid;    // 0..2303
  int rg = idx / 48, cg = idx % 48;
  int r0 = rg*2, c0 = cg*2;
  float entacc[2][2] = {{0.f,0.f},{0.f,0.f}};
  for (int ch=0; ch<CH; ++ch){
    const float* src = rimg + ((size_t)(n*CH+ch))*NPIX;
    float cur[4][4], stp[4][4];
    #pragma unroll
    for (int r=0;r<4;r++){
      int gr = r0-1+r;
      bool rok = (gr>=0 && gr<HH);
      #pragma unroll
      for (int c=0;c<4;c++){
        int gc = c0-1+c;
        if (rok && gc>=0 && gc<WW){
          float v = src[gr*96+gc];
          cur[r][c] = __expf(-50.f*v*v);
          stp[r][c] = __expf(6.6666667f*v);
        } else { cur[r][c]=0.f; stp[r][c]=1.f; }
      }
    }
    float S[2][2]={{0.f,0.f},{0.f,0.f}}, T[2][2]={{0.f,0.f},{0.f,0.f}};
    float rb = __expf(-0.22222222f);
    const float r2m = rb*rb;
    #pragma unroll
    for (int b=0;b<16;b++){
      float vs[2][4];
      #pragma unroll
      for (int rr=0;rr<2;rr++)
        #pragma unroll
        for (int c=0;c<4;c++)
          vs[rr][c] = cur[rr][c]+cur[rr+1][c]+cur[rr+2][c];
      #pragma unroll
      for (int rr=0;rr<2;rr++)
        #pragma unroll
        for (int cc=0;cc<2;cc++){
          float p = (vs[rr][cc]+vs[rr][cc+1]+vs[rr][cc+2])*(1.f/9.f);
          S[rr][cc] += p;
          T[rr][cc] += p*__logf(p+EPSF);
        }
      if (b<15){
        float m = rb;
        #pragma unroll
        for (int r=0;r<4;r++)
          #pragma unroll
          for (int c=0;c<4;c++)
            cur[r][c] *= stp[r][c]*m;
        rb *= r2m;
      }
    }
    #pragma unroll
    for (int rr=0;rr<2;rr++)
      #pragma unroll
      for (int cc=0;cc<2;cc++){
        float Sp = S[rr][cc]+EPSF;
        entacc[rr][cc] += __logf(Sp) - T[rr][cc]/Sp;
      }
  }
  #pragma unroll
  for (int rr=0;rr<2;rr++)
    #pragma unroll
    for (int cc=0;cc<2;cc++)
      ent[(size_t)n*NPIX + (size_t)(r0+rr)*96 + (c0+cc)] = entacc[rr][cc]*(1.f/3.f);
}

// ---------------- main gaussians pass: single pass, SW-pipelined double-buffer loads ----------------
__global__ __launch_bounds__(256) void k_main(const float* __restrict__ gauss,
                                              const float* __restrict__ status,
                                              const float* __restrict__ ent,
                                              float* __restrict__ miS,
                                              float* __restrict__ melN,
                                              float* __restrict__ mcelN,
                                              float* __restrict__ reS,
                                              float* __restrict__ ceS,
                                              unsigned int* __restrict__ gmax,
                                              float* __restrict__ hsG){
  __shared__ float st_sh[128];
  int tid = threadIdx.x;
  int lane = tid & 63;
  int tile = blockIdx.x;   // 0..17
  int b = blockIdx.y;      // 0..15
  if (tid < 128) st_sh[tid] = status[b*128 + tid];
  __syncthreads();
  int p2 = tile*256 + tid;                       // float2 index in 4608-wide plane
  const float2* __restrict__ g2 = (const float2*)gauss;
  const float2* __restrict__ e2 = (const float2*)ent;
  const float2* __restrict__ gp = g2 + (size_t)b*128*4608 + p2;  // (b, s=0, kp=0) base
  float2 re[4], se[4], ce[4];
  #pragma unroll
  for (int s=0;s<4;s++) re[s] = e2[(size_t)(b*4+s)*4608 + p2];
  #pragma unroll
  for (int s=0;s<4;s++){
    se[s] = re[(s+3)&3];
    ce[s].x = fmaxf(re[s].x, se[s].x) - se[s].x;
    ce[s].y = fmaxf(re[s].y, se[s].y) - se[s].y;
  }
  float2 am[4], ag[4], mi[4];
  #pragma unroll
  for (int s=0;s<4;s++){ am[s]=make_float2(0,0); ag[s]=make_float2(0,0); mi[s]=make_float2(0,0); }
  float hs = 0.f;
  float2 bufA[4][4], bufB[4][4];

#define LOADG(BUF, G) { \
  _Pragma("unroll") for (int s=0;s<4;s++){ \
    _Pragma("unroll") for (int j=0;j<4;j++){ \
      BUF[s][j] = gp[(size_t)(s*32 + (G)*4 + j)*4608]; } } }

#define PROCG(BUF, G) { \
  _Pragma("unroll") for (int j=0;j<4;j++){ \
    float2 ah[4]; \
    _Pragma("unroll") for (int s=0;s<4;s++){ \
      float2 g = BUF[s][j]; \
      float st = st_sh[s*32 + (G)*4 + j]; \
      float hx = fminf(fmaxf(g.x - 0.1f, 0.f)*3.5f, 1.f); \
      float hy = fminf(fmaxf(g.y - 0.1f, 0.f)*3.5f, 1.f); \
      if (b==0 && s==0 && ((G)*4+j)==0) hs = hx + hy; \
      ah[s].x = st*hx; ah[s].y = st*hy; \
      am[s].x += ah[s].x; am[s].y += ah[s].y; \
      ag[s].x += g.x;     ag[s].y += g.y; } \
    _Pragma("unroll") for (int s=0;s<4;s++){ \
      float2 sh = ah[(s+3)&3]; \
      float rx = se[s].x*(1.f-ah[s].x)*(1.f-sh.x) + re[s].x*ah[s].x + ce[s].x*(1.f-ah[s].x); \
      float ry = se[s].y*(1.f-ah[s].y)*(1.f-sh.y) + re[s].y*ah[s].y + ce[s].y*(1.f-ah[s].y); \
      mi[s].x += fminf(rx, re[s].x); \
      mi[s].y += fminf(ry, re[s].y); } } }

  LOADG(bufA, 0)
  LOADG(bufB, 1)
  PROCG(bufA, 0)
  LOADG(bufA, 2)
  PROCG(bufB, 1)
  LOADG(bufB, 3)
  PROCG(bufA, 2)
  LOADG(bufA, 4)
  PROCG(bufB, 3)
  LOADG(bufB, 5)
  PROCG(bufA, 4)
  LOADG(bufA, 6)
  PROCG(bufB, 5)
  LOADG(bufB, 7)
  PROCG(bufA, 6)
  PROCG(bufB, 7)
#undef LOADG
#undef PROCG

  #pragma unroll
  for (int s=0;s<4;s++){
    float qx = 1.f - fminf(am[s].x, 1.f);
    float qy = 1.f - fminf(am[s].y, 1.f);
    float r1 = wred_sum(re[s].x*qx + re[s].y*qy);
    float r2 = wred_sum(ce[s].x*qx + ce[s].y*qy);
    float r3 = wred_sum(re[s].x + re[s].y);
    float r4 = wred_sum(ce[s].x + ce[s].y);
    float r5 = wred_max(fmaxf(ag[s].x, ag[s].y));
    float r6 = wred_sum(mi[s].x + mi[s].y);
    if (lane==0){
      atomicAdd(&melN[b*4+s], r1);
      atomicAdd(&mcelN[b*4+s], r2);
      atomicAdd(&reS[b*4+s], r3);
      atomicAdd(&ceS[b*4+s], r4);
      atomicMax(&gmax[b*4+s], __float_as_uint(r5));
      atomicAdd(&miS[b*4+s], r6);
    }
  }
  if (b==0){
    float h = wred_sum(hs);
    if (lane==0) atomicAdd(hsG, h);
  }
}

// ---------------- finalization ----------------
__global__ __launch_bounds__(256) void k_final(const float* __restrict__ coords,
                                               const float* __restrict__ status,
                                               const float* __restrict__ miS,
                                               const float* __restrict__ melN,
                                               const float* __restrict__ mcelN,
                                               const float* __restrict__ reS,
                                               const float* __restrict__ ceS,
                                               const unsigned int* __restrict__ gmax,
                                               const float* __restrict__ hsG,
                                               float* __restrict__ out){
  __shared__ float wsum[4];
  int tid = threadIdx.x;
  int n = tid >> 2, q = tid & 3;   // n in 0..63, q selects 8 kp
  int s = n & 3;
  int np = (s==0) ? n+3 : n-1;
  float mc = 0.f, sl = 0.f;
  #pragma unroll
  for (int j=0;j<8;j++){
    int kp = q*8 + j;
    float dx = coords[(n*KPN+kp)*2+0] - coords[(np*KPN+kp)*2+0];
    float dy = coords[(n*KPN+kp)*2+1] - coords[(np*KPN+kp)*2+1];
    float st = status[n*KPN+kp];
    mc += sqrtf(dx*dx+dy*dy) * st * status[np*KPN+kp];
    sl += st;
  }
  mc += __shfl_xor(mc,1,64); mc += __shfl_xor(mc,2,64);
  sl += __shfl_xor(sl,1,64); sl += __shfl_xor(sl,2,64);
  float mint = 0.f;
  if (q==0){
    sl *= (1.f/KPN);
    float rsum = reS[n];
    float mel = melN[n]/(rsum+EPSF);
    float mcel = (s==0) ? 0.f : mcelN[n]/(ceS[n]+EPSF);
    float rc = (rsum - miS[n]*(1.f/KPN)) / hsG[0];
    float itl = rc + 0.1f*mc;
    float ovl = fmaxf(__uint_as_float(gmax[n]) - 1.5f, 0.f)*(1.f/KPN);
    mint = 100.f*mel + 100.f*mcel + itl + 10.f*ovl + (1.f-mel)*2.5f*sl;
  }
  float r = wred_sum(mint);
  if ((tid&63)==0) wsum[tid>>6] = r;
  __syncthreads();
  if (tid==0) out[0] = (wsum[0]+wsum[1]+wsum[2]+wsum[3])*(1.f/64.f);
}

extern "C" void kernel_launch(void* const* d_in, const int* in_sizes, int n_in,
                              void* d_out, int out_size, void* d_ws, size_t ws_size,
                              hipStream_t stream){
  const float* coords = (const float*)d_in[0];
  const float* gauss  = (const float*)d_in[1];
  const float* status = (const float*)d_in[2];
  const float* images = (const float*)d_in[3];
  float* out = (float*)d_out;
  float* rimg = (float*)d_ws;                          // 1,769,472 f32
  float* ent  = rimg + (size_t)NIMG*CH*NPIX;           // 589,824 f32
  float* miS  = ent + (size_t)NIMG*NPIX;               // 64
  float* melN = miS + 64;
  float* mcelN = melN + 64;
  float* reS   = mcelN + 64;
  float* ceS   = reS + 64;
  unsigned int* gmax = (unsigned int*)(ceS + 64);      // 64
  float* hsG = (float*)(gmax + 64);                    // 1
  hipMemsetAsync(miS, 0, (6*64 + 1)*sizeof(float), stream);
  k_resize<<<(NIMG*CH*NPIX + 255)/256, 256, 0, stream>>>(images, rimg);
  k_entropy<<<dim3(9,64), 256, 0, stream>>>(rimg, ent);
  k_main<<<dim3(18,16), 256, 0, stream>>>(gauss, status, ent, miS, melN, mcelN, reS, ceS, gmax, hsG);
  k_final<<<1,256,0,stream>>>(coords, status, miS, melN, mcelN, reS, ceS, gmax, hsG, out);
}